// Round 1
// baseline (566.175 us; speedup 1.0000x reference)
//
#include <hip/hip_runtime.h>
#include <hip/hip_bf16.h>
#include <stdint.h>

// BitNet b1.58 linear: out[M,N] = x[M,K] @ (ternary(W)*scale)[N,K]^T + bias[N]
// M=8192, N=4096, K=4096 (computed from in_sizes at launch).
//
// Strategy: ternary weights are EXACT in bf16; x->bf16 costs ~0.2 absmax
// (threshold 4.86). So: reduce |W| -> scale, quantize W->bf16 ternary,
// convert x->bf16, then m97-style 128x128 MFMA GEMM (global_load_lds w=16,
// 16x16x32 bf16), scale+bias in fp32 epilogue.

#define BM 128
#define BN 128
#define BK 64

typedef __bf16 bf16x8 __attribute__((ext_vector_type(8)));
typedef float f32x4 __attribute__((ext_vector_type(4)));

__device__ __forceinline__ unsigned short f2bf_rne(float f) {
  union { float f; unsigned int u; } v; v.f = f;
  unsigned int u = v.u;
  u += 0x7FFFu + ((u >> 16) & 1u);
  return (unsigned short)(u >> 16);
}

// ---------------------------------------------------------------- reduction
// sum(|w|) -> double ws[0]. fp32 per-thread/wave partials, fp64 atomic of
// 1024 block partials => scale deterministic to ~1e-13 rel (minimizes
// ternary flips at the 2/3 threshold vs the numpy reference).
__global__ void absum_kernel(const float4* __restrict__ w, int n4,
                             double* __restrict__ out) {
  float s = 0.f;
  for (int i = blockIdx.x * blockDim.x + threadIdx.x; i < n4;
       i += gridDim.x * blockDim.x) {
    float4 v = w[i];
    s += fabsf(v.x) + fabsf(v.y) + fabsf(v.z) + fabsf(v.w);
  }
#pragma unroll
  for (int off = 32; off > 0; off >>= 1) s += __shfl_down(s, off);
  __shared__ float partial[4];
  if ((threadIdx.x & 63) == 0) partial[threadIdx.x >> 6] = s;
  __syncthreads();
  if (threadIdx.x == 0)
    atomicAdd(out, (double)(partial[0] + partial[1] + partial[2] + partial[3]));
}

// ---------------------------------------------------------------- quantize W
// q = bf16 bits of {-1,0,+1}; comparison replicates ref's fp32 w/scale vs
// float(2/3). (clip(...,±10) can't change the ternary outcome.)
__global__ void quant_kernel(const float4* __restrict__ w, int n4,
                             const double* __restrict__ sum, double inv_cnt,
                             ushort4* __restrict__ q) {
  float scale = (float)fmin(fmax(sum[0] * inv_cnt, 1e-5), 1000.0);
  const float T = 2.0f / 3.0f;
  for (int i = blockIdx.x * blockDim.x + threadIdx.x; i < n4;
       i += gridDim.x * blockDim.x) {
    float4 v = w[i];
    ushort4 o;
    float nx = v.x / scale, ny = v.y / scale, nz = v.z / scale, nw = v.w / scale;
    o.x = (nx > T) ? 0x3F80u : ((nx < -T) ? 0xBF80u : 0u);
    o.y = (ny > T) ? 0x3F80u : ((ny < -T) ? 0xBF80u : 0u);
    o.z = (nz > T) ? 0x3F80u : ((nz < -T) ? 0xBF80u : 0u);
    o.w = (nw > T) ? 0x3F80u : ((nw < -T) ? 0xBF80u : 0u);
    q[i] = o;
  }
}

// ---------------------------------------------------------------- x -> bf16
__global__ void xcvt_kernel(const float4* __restrict__ x, int n4,
                            ushort4* __restrict__ xb) {
  for (int i = blockIdx.x * blockDim.x + threadIdx.x; i < n4;
       i += gridDim.x * blockDim.x) {
    float4 v = x[i];
    ushort4 o;
    o.x = f2bf_rne(v.x);
    o.y = f2bf_rne(v.y);
    o.z = f2bf_rne(v.z);
    o.w = f2bf_rne(v.w);
    xb[i] = o;
  }
}

// ---------------------------------------------------------------- GEMM
// m97 structure: 256 thr = 4 waves, 128x128 tile, BK=64, global_load_lds
// width 16 staging (LDS layout unpadded row-major [row][BK] as required by
// wave-uniform-base + lane*16 semantics), 2-barrier K-loop, 4x4 16x16x32
// bf16 MFMA per wave, fp32 scale+bias epilogue.
__global__ void gemm_kernel(const ushort* __restrict__ xb,   // [M,K] bf16 bits
                            const ushort* __restrict__ qb,   // [N,K] bf16 bits
                            const float* __restrict__ bias,  // [N]
                            const double* __restrict__ sum,
                            float* __restrict__ out,         // [M,N]
                            int M, int N, int K, double inv_cnt) {
  __shared__ __align__(16) ushort As[BM * BK];
  __shared__ __align__(16) ushort Bs[BN * BK];

  const int t = threadIdx.x;
  const int wave = t >> 6;
  const int lane = t & 63;
  const int m0 = blockIdx.y * BM;
  const int n0 = blockIdx.x * BN;

  const int wr = (wave >> 1) * 64;  // wave's m-offset in tile
  const int wc = (wave & 1) * 64;   // wave's n-offset in tile
  const int lm = lane & 15;
  const int lk = lane >> 4;

  // staging: per wave, 4 instrs each for A and B; instr s covers rows
  // [wave*32 + s*8, +8) of the tile; lane l -> row +l/8, col (l%8)*8.
  const int srow = lane >> 3;
  const int scol = (lane & 7) * 8;
  const ushort* ag = xb + (size_t)(m0 + wave * 32 + srow) * K + scol;
  const ushort* bg = qb + (size_t)(n0 + wave * 32 + srow) * K + scol;
  ushort* al = &As[(wave * 32) * BK];  // wave-uniform LDS base
  ushort* bl = &Bs[(wave * 32) * BK];

  f32x4 acc[4][4] = {};

  for (int k0 = 0; k0 < K; k0 += BK) {
#pragma unroll
    for (int s = 0; s < 4; ++s) {
      __builtin_amdgcn_global_load_lds(
          (const __attribute__((address_space(1))) void*)(ag + (size_t)s * 8 * K),
          (__attribute__((address_space(3))) void*)(al + s * 8 * BK), 16, 0, 0);
      __builtin_amdgcn_global_load_lds(
          (const __attribute__((address_space(1))) void*)(bg + (size_t)s * 8 * K),
          (__attribute__((address_space(3))) void*)(bl + s * 8 * BK), 16, 0, 0);
    }
    __syncthreads();  // drains vmcnt(0): LDS tiles complete

#pragma unroll
    for (int ks = 0; ks < 2; ++ks) {
      bf16x8 af[4], bf[4];
#pragma unroll
      for (int i = 0; i < 4; ++i)
        af[i] = *(const bf16x8*)&As[(wr + i * 16 + lm) * BK + ks * 32 + lk * 8];
#pragma unroll
      for (int j = 0; j < 4; ++j)
        bf[j] = *(const bf16x8*)&Bs[(wc + j * 16 + lm) * BK + ks * 32 + lk * 8];
#pragma unroll
      for (int i = 0; i < 4; ++i)
#pragma unroll
        for (int j = 0; j < 4; ++j)
          acc[i][j] = __builtin_amdgcn_mfma_f32_16x16x32_bf16(af[i], bf[j],
                                                             acc[i][j], 0, 0, 0);
    }
    __syncthreads();  // protect LDS from next iteration's staging
    ag += BK;
    bg += BK;
  }

  float scale = (float)fmin(fmax(sum[0] * inv_cnt, 1e-5), 1000.0);

  // C/D layout (m89-verified): col = lane&15, row = (lane>>4)*4 + reg
#pragma unroll
  for (int j = 0; j < 4; ++j) {
    const int col = n0 + wc + j * 16 + lm;
    const float bv = bias[col];
#pragma unroll
    for (int i = 0; i < 4; ++i) {
      const int row = m0 + wr + i * 16 + lk * 4;
      float* op = out + (size_t)row * N + col;
#pragma unroll
      for (int r = 0; r < 4; ++r)
        op[(size_t)r * N] = acc[i][j][r] * scale + bv;
    }
  }
}

// ---------------------------------------------------------------- launch
extern "C" void kernel_launch(void* const* d_in, const int* in_sizes, int n_in,
                              void* d_out, int out_size, void* d_ws,
                              size_t ws_size, hipStream_t stream) {
  const float* x = (const float*)d_in[0];
  const float* w = (const float*)d_in[1];
  const float* bias = (const float*)d_in[2];
  float* out = (float*)d_out;

  const int DOUT = in_sizes[2];        // 4096
  const int DIN = in_sizes[1] / DOUT;  // 4096
  const int M = in_sizes[0] / DIN;     // 8192
  const int N = DOUT, K = DIN;

  char* ws = (char*)d_ws;
  double* sum = (double*)ws;                                   // 8 B
  ushort* xb = (ushort*)(ws + 256);                            // M*K*2 B
  ushort* qb = (ushort*)(ws + 256 + (size_t)M * K * 2);        // N*K*2 B

  const double inv_cnt = 1.0 / ((double)N * (double)K);

  hipMemsetAsync(d_ws, 0, 8, stream);

  const int wn4 = (N * K) / 4;
  absum_kernel<<<1024, 256, 0, stream>>>((const float4*)w, wn4, sum);
  quant_kernel<<<2048, 256, 0, stream>>>((const float4*)w, wn4, sum, inv_cnt,
                                         (ushort4*)qb);
  const int xn4 = (M * K) / 4;
  xcvt_kernel<<<4096, 256, 0, stream>>>((const float4*)x, xn4, (ushort4*)xb);

  dim3 grid(N / BN, M / BM);
  gemm_kernel<<<grid, 256, 0, stream>>>(xb, qb, bias, sum, out, M, N, K,
                                        inv_cnt);
}

// Round 2
// 541.131 us; speedup vs baseline: 1.0463x; 1.0463x over previous
//
#include <hip/hip_runtime.h>
#include <hip/hip_bf16.h>
#include <stdint.h>

// BitNet b1.58 linear: out[M,N] = x[M,K] @ (ternary(W)*scale)[N,K]^T + bias[N]
// M=8192, N=4096, K=4096.
//
// R1 -> R2: XOR-swizzled LDS layout to kill the 16-way bank conflict
// (SQ_LDS_BANK_CONFLICT was 1.0e8 = ~52% of GEMM cycles). LDS slot p of row r
// holds global 16B-chunk p^(r&7); staging lane l fetches global chunk
// (l&7)^(l>>3); fragment reads use slot kc^(lm&7) -> 2-way max (free, m136).
// Prepass kernels widened to 16-B stores (8 elems/thread).

#define BM 128
#define BN 128
#define BK 64

typedef __bf16 bf16x8 __attribute__((ext_vector_type(8)));
typedef float f32x4 __attribute__((ext_vector_type(4)));
typedef unsigned short u16x8 __attribute__((ext_vector_type(8)));

__device__ __forceinline__ unsigned short f2bf_rne(float f) {
  union { float f; unsigned int u; } v; v.f = f;
  unsigned int u = v.u;
  u += 0x7FFFu + ((u >> 16) & 1u);
  return (unsigned short)(u >> 16);
}

// ---------------------------------------------------------------- reduction
__global__ void absum_kernel(const float4* __restrict__ w, int n4,
                             double* __restrict__ out) {
  float s = 0.f;
  for (int i = blockIdx.x * blockDim.x + threadIdx.x; i < n4;
       i += gridDim.x * blockDim.x) {
    float4 v = w[i];
    s += fabsf(v.x) + fabsf(v.y) + fabsf(v.z) + fabsf(v.w);
  }
#pragma unroll
  for (int off = 32; off > 0; off >>= 1) s += __shfl_down(s, off);
  __shared__ float partial[4];
  if ((threadIdx.x & 63) == 0) partial[threadIdx.x >> 6] = s;
  __syncthreads();
  if (threadIdx.x == 0)
    atomicAdd(out, (double)(partial[0] + partial[1] + partial[2] + partial[3]));
}

// ---------------------------------------------------------------- quantize W
// 8 elems/thread -> one 16-B store. Division kept (correctly-rounded, matches
// the numpy ref's fp32 w/scale at the 2/3 threshold).
__global__ void quant_kernel(const float4* __restrict__ w, int n8,
                             const double* __restrict__ sum, double inv_cnt,
                             u16x8* __restrict__ q) {
  float scale = (float)fmin(fmax(sum[0] * inv_cnt, 1e-5), 1000.0);
  const float T = 2.0f / 3.0f;
  for (int i = blockIdx.x * blockDim.x + threadIdx.x; i < n8;
       i += gridDim.x * blockDim.x) {
    float4 a = w[2 * i], b = w[2 * i + 1];
    float f[8] = {a.x, a.y, a.z, a.w, b.x, b.y, b.z, b.w};
    u16x8 o;
#pragma unroll
    for (int j = 0; j < 8; ++j) {
      float n = f[j] / scale;
      o[j] = (n > T) ? 0x3F80u : ((n < -T) ? 0xBF80u : 0u);
    }
    q[i] = o;
  }
}

// ---------------------------------------------------------------- x -> bf16
__global__ void xcvt_kernel(const float4* __restrict__ x, int n8,
                            u16x8* __restrict__ xb) {
  for (int i = blockIdx.x * blockDim.x + threadIdx.x; i < n8;
       i += gridDim.x * blockDim.x) {
    float4 a = x[2 * i], b = x[2 * i + 1];
    float f[8] = {a.x, a.y, a.z, a.w, b.x, b.y, b.z, b.w};
    u16x8 o;
#pragma unroll
    for (int j = 0; j < 8; ++j) o[j] = f2bf_rne(f[j]);
    xb[i] = o;
  }
}

// ---------------------------------------------------------------- GEMM
__global__ void gemm_kernel(const ushort* __restrict__ xb,   // [M,K] bf16 bits
                            const ushort* __restrict__ qb,   // [N,K] bf16 bits
                            const float* __restrict__ bias,  // [N]
                            const double* __restrict__ sum,
                            float* __restrict__ out,         // [M,N]
                            int M, int N, int K, double inv_cnt) {
  __shared__ __align__(16) ushort As[BM * BK];
  __shared__ __align__(16) ushort Bs[BN * BK];

  const int t = threadIdx.x;
  const int wave = t >> 6;
  const int lane = t & 63;
  const int m0 = blockIdx.y * BM;
  const int n0 = blockIdx.x * BN;

  const int wr = (wave >> 1) * 64;  // wave's m-offset in tile
  const int wc = (wave & 1) * 64;   // wave's n-offset in tile
  const int lm = lane & 15;
  const int lk = lane >> 4;

  // staging: lane l -> LDS slot l&7 of row l>>3; must carry global chunk
  // (l&7)^(l>>3)  (XOR swizzle).
  const int srow = lane >> 3;
  const int schunk = (lane & 7) ^ srow;
  const ushort* ag = xb + (size_t)(m0 + wave * 32 + srow) * K + schunk * 8;
  const ushort* bg = qb + (size_t)(n0 + wave * 32 + srow) * K + schunk * 8;
  ushort* al = &As[(wave * 32) * BK];  // wave-uniform LDS base
  ushort* bl = &Bs[(wave * 32) * BK];

  f32x4 acc[4][4] = {};

  for (int k0 = 0; k0 < K; k0 += BK) {
#pragma unroll
    for (int s = 0; s < 4; ++s) {
      __builtin_amdgcn_global_load_lds(
          (const __attribute__((address_space(1))) void*)(ag + (size_t)s * 8 * K),
          (__attribute__((address_space(3))) void*)(al + s * 8 * BK), 16, 0, 0);
      __builtin_amdgcn_global_load_lds(
          (const __attribute__((address_space(1))) void*)(bg + (size_t)s * 8 * K),
          (__attribute__((address_space(3))) void*)(bl + s * 8 * BK), 16, 0, 0);
    }
    __syncthreads();

#pragma unroll
    for (int ks = 0; ks < 2; ++ks) {
      bf16x8 af[4], bf[4];
#pragma unroll
      for (int i = 0; i < 4; ++i) {
        const int row = wr + i * 16 + lm;
        const int slot = (ks * 4 + lk) ^ (lm & 7);
        af[i] = *(const bf16x8*)&As[row * BK + slot * 8];
      }
#pragma unroll
      for (int j = 0; j < 4; ++j) {
        const int row = wc + j * 16 + lm;
        const int slot = (ks * 4 + lk) ^ (lm & 7);
        bf[j] = *(const bf16x8*)&Bs[row * BK + slot * 8];
      }
#pragma unroll
      for (int i = 0; i < 4; ++i)
#pragma unroll
        for (int j = 0; j < 4; ++j)
          acc[i][j] = __builtin_amdgcn_mfma_f32_16x16x32_bf16(af[i], bf[j],
                                                             acc[i][j], 0, 0, 0);
    }
    __syncthreads();
    ag += BK;
    bg += BK;
  }

  float scale = (float)fmin(fmax(sum[0] * inv_cnt, 1e-5), 1000.0);

  // C/D layout (m89-verified): col = lane&15, row = (lane>>4)*4 + reg
#pragma unroll
  for (int j = 0; j < 4; ++j) {
    const int col = n0 + wc + j * 16 + lm;
    const float bv = bias[col];
#pragma unroll
    for (int i = 0; i < 4; ++i) {
      const int row = m0 + wr + i * 16 + lk * 4;
      float* op = out + (size_t)row * N + col;
#pragma unroll
      for (int r = 0; r < 4; ++r)
        op[(size_t)r * N] = acc[i][j][r] * scale + bv;
    }
  }
}

// ---------------------------------------------------------------- launch
extern "C" void kernel_launch(void* const* d_in, const int* in_sizes, int n_in,
                              void* d_out, int out_size, void* d_ws,
                              size_t ws_size, hipStream_t stream) {
  const float* x = (const float*)d_in[0];
  const float* w = (const float*)d_in[1];
  const float* bias = (const float*)d_in[2];
  float* out = (float*)d_out;

  const int DOUT = in_sizes[2];        // 4096
  const int DIN = in_sizes[1] / DOUT;  // 4096
  const int M = in_sizes[0] / DIN;     // 8192
  const int N = DOUT, K = DIN;

  char* ws = (char*)d_ws;
  double* sum = (double*)ws;                                   // 8 B
  ushort* xb = (ushort*)(ws + 256);                            // M*K*2 B
  ushort* qb = (ushort*)(ws + 256 + (size_t)M * K * 2);        // N*K*2 B

  const double inv_cnt = 1.0 / ((double)N * (double)K);

  hipMemsetAsync(d_ws, 0, 8, stream);

  const int wn4 = (N * K) / 4;
  const int wn8 = (N * K) / 8;
  absum_kernel<<<2048, 256, 0, stream>>>((const float4*)w, wn4, sum);
  quant_kernel<<<4096, 256, 0, stream>>>((const float4*)w, wn8, sum, inv_cnt,
                                         (u16x8*)qb);
  const int xn8 = (M * K) / 8;
  xcvt_kernel<<<8192, 256, 0, stream>>>((const float4*)x, xn8, (u16x8*)xb);

  dim3 grid(N / BN, M / BM);
  gemm_kernel<<<grid, 256, 0, stream>>>(xb, qb, bias, sum, out, M, N, K,
                                        inv_cnt);
}